// Round 1
// baseline (940.344 us; speedup 1.0000x reference)
//
#include <hip/hip_runtime.h>
#include <hip/hip_bf16.h>

#define S_LEN 8192
#define D_MODEL 512
#define NH 8
#define HD 64
#define WIN 256
#define NB 2

typedef __hip_bfloat16 bf16;

// ---------------------------------------------------------------------------
// QKV projection: out = (x @ W + b) * scale, stored bf16 head-major [B*H,S,HD]
// M=16384, N=512, K=512. 64x64 tile, BK=16, 256 threads, 4x4 per thread.
// ---------------------------------------------------------------------------
__global__ __launch_bounds__(256) void proj_kernel(
    const float* __restrict__ x, const float* __restrict__ Wm,
    const float* __restrict__ bias, bf16* __restrict__ dst, float scale)
{
    __shared__ float As[16][64];   // As[k][m]  (x tile, transposed)
    __shared__ float Bs[16][64];   // Bs[k][n]

    const int tid  = threadIdx.x;
    const int row0 = blockIdx.y * 64;
    const int col0 = blockIdx.x * 64;
    const int ty = tid >> 4, tx = tid & 15;
    const int t4 = tid * 4;
    const int ai = t4 >> 4, aj = t4 & 15;   // A-load: row ai (0..63), k-col aj
    const int bj = t4 >> 6, bi = t4 & 63;   // B-load: k-row bj (0..15), col bi

    float acc[4][4] = {};

    for (int kb = 0; kb < D_MODEL; kb += 16) {
        float4 av = *(const float4*)(x  + (size_t)(row0 + ai) * D_MODEL + kb + aj);
        float4 bv = *(const float4*)(Wm + (size_t)(kb + bj)  * D_MODEL + col0 + bi);
        As[aj + 0][ai] = av.x;
        As[aj + 1][ai] = av.y;
        As[aj + 2][ai] = av.z;
        As[aj + 3][ai] = av.w;
        *(float4*)(&Bs[bj][bi]) = bv;
        __syncthreads();
#pragma unroll
        for (int k = 0; k < 16; ++k) {
            float a[4], b[4];
#pragma unroll
            for (int ii = 0; ii < 4; ++ii) a[ii] = As[k][ty * 4 + ii];
#pragma unroll
            for (int jj = 0; jj < 4; ++jj) b[jj] = Bs[k][tx * 4 + jj];
#pragma unroll
            for (int ii = 0; ii < 4; ++ii)
#pragma unroll
                for (int jj = 0; jj < 4; ++jj) acc[ii][jj] += a[ii] * b[jj];
        }
        __syncthreads();
    }

#pragma unroll
    for (int ii = 0; ii < 4; ++ii) {
        const int m = row0 + ty * 4 + ii;
        const int b = m >> 13;            // m / S_LEN
        const int s = m & (S_LEN - 1);
#pragma unroll
        for (int jj = 0; jj < 4; ++jj) {
            const int n = col0 + tx * 4 + jj;
            const int h = n >> 6, d = n & 63;
            const float v = (acc[ii][jj] + bias[n]) * scale;
            dst[(((size_t)(b * NH + h)) * S_LEN + s) * HD + d] = __float2bfloat16(v);
        }
    }
}

// ---------------------------------------------------------------------------
// Sliding-window attention, online softmax.
// Block = 256 threads = 64 queries x 4 dim-groups (16 dims each).
// Grid = (B*H, S/64). Keys staged 64-at-a-time in LDS as fp32.
// ---------------------------------------------------------------------------
__global__ __launch_bounds__(256) void attn_kernel(
    const bf16* __restrict__ qw, const bf16* __restrict__ kw,
    const bf16* __restrict__ vw, float* __restrict__ out)
{
    __shared__ float ksh[64][64];
    __shared__ float vsh[64][64];

    const int bh  = blockIdx.x;            // 0..15
    const int qt0 = blockIdx.y * 64;       // query tile base
    const int tid = threadIdx.x;
    const int qi  = tid >> 2;              // query within tile (0..63)
    const int dg  = tid & 3;               // dim group (0..3)
    const int qs  = qt0 + qi;              // global query position
    const int d0  = dg * 16;
    const size_t base = (size_t)bh * S_LEN * HD;

    float qreg[16];
#pragma unroll
    for (int i = 0; i < 16; ++i)
        qreg[i] = __bfloat162float(qw[base + (size_t)qs * HD + d0 + i]);

    float acc[16] = {};
    float m = -1e30f, l = 0.0f;

    for (int kt = qt0 - WIN; kt <= qt0 + 63 + WIN; kt += 64) {
        if (kt + 63 < 0 || kt >= S_LEN) continue;   // block-uniform

        // stage k,v tile (zero-fill OOB rows); consecutive lanes -> consecutive
        // cols: coalesced global, conflict-free LDS writes
#pragma unroll
        for (int i = 0; i < 16; ++i) {
            const int idx = tid + 256 * i;          // 0..4095
            const int r = idx >> 6, c = idx & 63;
            const int j = kt + r;
            float kvv = 0.0f, vvv = 0.0f;
            if (j >= 0 && j < S_LEN) {
                const size_t o = base + (size_t)j * HD + c;
                kvv = __bfloat162float(kw[o]);
                vvv = __bfloat162float(vw[o]);
            }
            ksh[r][c] = kvv;
            vsh[r][c] = vvv;
        }
        __syncthreads();

        for (int jj = 0; jj < 64; ++jj) {
            const int j = kt + jj;
            float dot = 0.0f;
#pragma unroll
            for (int i = 0; i < 16; ++i) dot += qreg[i] * ksh[jj][d0 + i];
            dot += __shfl_xor(dot, 1);
            dot += __shfl_xor(dot, 2);              // full score in all 4 lanes

            const bool valid = (j >= 0) && (j < S_LEN) &&
                               (j >= qs - WIN) && (j <= qs + WIN);
            const float sc = valid ? dot : -1e30f;
            const float mn = fmaxf(m, sc);
            const float alpha = __expf(m - mn);     // m==mn==-1e30 -> 1, but l=acc=0
            const float p = valid ? __expf(sc - mn) : 0.0f;
            l = l * alpha + p;
            m = mn;
#pragma unroll
            for (int i = 0; i < 16; ++i)
                acc[i] = acc[i] * alpha + p * vsh[jj][d0 + i];
        }
        __syncthreads();
    }

    const float rl = 1.0f / l;
    const int b = bh >> 3, h = bh & 7;
    float* op = out + ((size_t)(b * S_LEN + qs)) * D_MODEL + h * HD + d0;
#pragma unroll
    for (int i = 0; i < 16; ++i) op[i] = acc[i] * rl;
}

// ---------------------------------------------------------------------------
extern "C" void kernel_launch(void* const* d_in, const int* in_sizes, int n_in,
                              void* d_out, int out_size, void* d_ws, size_t ws_size,
                              hipStream_t stream)
{
    const float* x  = (const float*)d_in[0];
    const float* Wq = (const float*)d_in[1];
    const float* bq = (const float*)d_in[2];
    const float* Wk = (const float*)d_in[3];
    const float* bk = (const float*)d_in[4];
    const float* Wv = (const float*)d_in[5];
    const float* bv = (const float*)d_in[6];
    float* out = (float*)d_out;

    const size_t n_elem = (size_t)NB * NH * S_LEN * HD;   // 8,388,608
    bf16* qw = (bf16*)d_ws;
    bf16* kw = qw + n_elem;
    bf16* vw = kw + n_elem;

    dim3 pgrid(D_MODEL / 64, (NB * S_LEN) / 64);           // (8, 256)
    proj_kernel<<<pgrid, 256, 0, stream>>>(x, Wq, bq, qw, 0.125f);
    proj_kernel<<<pgrid, 256, 0, stream>>>(x, Wk, bk, kw, 1.0f);
    proj_kernel<<<pgrid, 256, 0, stream>>>(x, Wv, bv, vw, 1.0f);

    dim3 agrid(NB * NH, S_LEN / 64);                       // (16, 128)
    attn_kernel<<<agrid, 256, 0, stream>>>(qw, kw, vw, out);
}

// Round 2
// 538.495 us; speedup vs baseline: 1.7462x; 1.7462x over previous
//
#include <hip/hip_runtime.h>
#include <hip/hip_bf16.h>

#define S_LEN 8192
#define D_MODEL 512
#define NH 8
#define HD 64
#define WIN 256
#define NB 2

typedef __hip_bfloat16 bf16;
typedef __attribute__((ext_vector_type(8))) short short8;
typedef __attribute__((ext_vector_type(4))) float f32x4;

static __device__ __forceinline__ short f2bf(float f) {
    bf16 h = __float2bfloat16(f);
    return *reinterpret_cast<short*>(&h);
}

// ---------------------------------------------------------------------------
// QKV projection: out = (x @ W + b) * scale, stored bf16 head-major [B*H,S,HD]
// (unchanged from round 1 — fp32 vector GEMM; MFMA conversion is next round)
// ---------------------------------------------------------------------------
__global__ __launch_bounds__(256) void proj_kernel(
    const float* __restrict__ x, const float* __restrict__ Wm,
    const float* __restrict__ bias, bf16* __restrict__ dst, float scale)
{
    __shared__ float As[16][64];
    __shared__ float Bs[16][64];

    const int tid  = threadIdx.x;
    const int row0 = blockIdx.y * 64;
    const int col0 = blockIdx.x * 64;
    const int ty = tid >> 4, tx = tid & 15;
    const int t4 = tid * 4;
    const int ai = t4 >> 4, aj = t4 & 15;
    const int bj = t4 >> 6, bi = t4 & 63;

    float acc[4][4] = {};

    for (int kb = 0; kb < D_MODEL; kb += 16) {
        float4 av = *(const float4*)(x  + (size_t)(row0 + ai) * D_MODEL + kb + aj);
        float4 bv = *(const float4*)(Wm + (size_t)(kb + bj)  * D_MODEL + col0 + bi);
        As[aj + 0][ai] = av.x;
        As[aj + 1][ai] = av.y;
        As[aj + 2][ai] = av.z;
        As[aj + 3][ai] = av.w;
        *(float4*)(&Bs[bj][bi]) = bv;
        __syncthreads();
#pragma unroll
        for (int k = 0; k < 16; ++k) {
            float a[4], b[4];
#pragma unroll
            for (int ii = 0; ii < 4; ++ii) a[ii] = As[k][ty * 4 + ii];
#pragma unroll
            for (int jj = 0; jj < 4; ++jj) b[jj] = Bs[k][tx * 4 + jj];
#pragma unroll
            for (int ii = 0; ii < 4; ++ii)
#pragma unroll
                for (int jj = 0; jj < 4; ++jj) acc[ii][jj] += a[ii] * b[jj];
        }
        __syncthreads();
    }

#pragma unroll
    for (int ii = 0; ii < 4; ++ii) {
        const int m = row0 + ty * 4 + ii;
        const int b = m >> 13;
        const int s = m & (S_LEN - 1);
#pragma unroll
        for (int jj = 0; jj < 4; ++jj) {
            const int n = col0 + tx * 4 + jj;
            const int h = n >> 6, d = n & 63;
            const float v = (acc[ii][jj] + bias[n]) * scale;
            dst[(((size_t)(b * NH + h)) * S_LEN + s) * HD + d] = __float2bfloat16(v);
        }
    }
}

// ---------------------------------------------------------------------------
// Flash-style MFMA sliding-window attention.
// Block = 256 threads = 4 waves; wave w owns queries q0 = qt0+16w .. +15.
// Per 64-key tile: QK^T via 8 mfma_16x16x32_bf16 (K frags direct from global),
// online softmax in C-layout regs, P -> LDS -> A-layout, PV via 8 MFMAs
// (V staged transposed in LDS).
// MFMA layouts (verified, m89/m91): C/D col=lane&15, row=(lane>>4)*4+reg;
// A[m=lane&15][k=(lane>>4)*8+j]; B[n=lane&15][k=(lane>>4)*8+j] (computes A.B^T).
// ---------------------------------------------------------------------------
__global__ __launch_bounds__(256) void attn_mfma_kernel(
    const bf16* __restrict__ qw, const bf16* __restrict__ kw,
    const bf16* __restrict__ vw, float* __restrict__ out)
{
    // pad rows to 72 shorts (144 B) -> worst LDS aliasing is 2-way (free, m136)
    __shared__ __align__(16) short Vsh[64][72];      // [dim][key] (transposed)
    __shared__ __align__(16) short Psh[4][16][72];   // per-wave [query][key]

    const int bh   = blockIdx.x;             // 0..15
    const int qt0  = blockIdx.y * 64;
    const int tid  = threadIdx.x;
    const int w    = tid >> 6;
    const int lane = tid & 63;
    const int col  = lane & 15;              // MFMA n/m index
    const int kg   = lane >> 4;              // k-group (0..3)
    const int q0   = qt0 + w * 16;
    const size_t base = (size_t)bh * S_LEN * HD;

    const short* qg = (const short*)qw;
    const short* kgp = (const short*)kw;
    const short* vgp = (const short*)vw;

    // Q A-fragments (held all loop): A[m=col][k = kg*8 + j (+32)]
    const short* qptr = qg + base + (size_t)(q0 + col) * HD + kg * 8;
    const short8 qA0 = *(const short8*)(qptr);
    const short8 qA1 = *(const short8*)(qptr + 32);

    const f32x4 zero4 = {0.f, 0.f, 0.f, 0.f};
    f32x4 Oacc[4] = {zero4, zero4, zero4, zero4};
    float mrow[4] = {-1e30f, -1e30f, -1e30f, -1e30f};
    float lrow[4] = {0.f, 0.f, 0.f, 0.f};

    // V staging: thread handles key = tid&63, dims vd0..vd0+15
    const int vkey = tid & 63;
    const int vd0  = (tid >> 6) * 16;

    for (int kt = qt0 - WIN; kt <= qt0 + WIN; kt += 64) {
        if (kt + 63 < 0 || kt >= S_LEN) continue;       // block-uniform

        __syncthreads();                                 // protect Vsh reuse
        {
            const int j  = kt + vkey;
            const int jc = j < 0 ? 0 : (j >= S_LEN ? S_LEN - 1 : j);
            const short* vp = vgp + base + (size_t)jc * HD + vd0;
            const short8 v0 = *(const short8*)(vp);
            const short8 v1 = *(const short8*)(vp + 8);
            // lanes span keys 0..63 -> 32 banks, 2-way b16 pairs: conflict-free
#pragma unroll
            for (int i = 0; i < 8; ++i) {
                Vsh[vd0 + i][vkey]     = v0[i];
                Vsh[vd0 + 8 + i][vkey] = v1[i];
            }
        }
        __syncthreads();

        const bool need_mask = (kt < 0) || (kt + 63 >= S_LEN) ||
                               (kt == qt0 - WIN) || (kt == qt0 + WIN);

        // ---- QK^T ----
        f32x4 sc[4];
#pragma unroll
        for (int t = 0; t < 4; ++t) {
            const int j  = kt + 16 * t + col;
            const int jc = j < 0 ? 0 : (j >= S_LEN ? S_LEN - 1 : j);
            const short* kp = kgp + base + (size_t)jc * HD + kg * 8;
            const short8 kB0 = *(const short8*)(kp);
            const short8 kB1 = *(const short8*)(kp + 32);
            f32x4 a = zero4;
            a = __builtin_amdgcn_mfma_f32_16x16x32_bf16(qA0, kB0, a, 0, 0, 0);
            a = __builtin_amdgcn_mfma_f32_16x16x32_bf16(qA1, kB1, a, 0, 0, 0);
            sc[t] = a;
        }

        // ---- online softmax (rows = kg*4 + r, 16 lanes per row group) ----
        float p[4][4];
        float alpha[4];
#pragma unroll
        for (int r = 0; r < 4; ++r) {
            float st[4];
#pragma unroll
            for (int t = 0; t < 4; ++t) st[t] = sc[t][r];
            if (need_mask) {
                const int qq = q0 + kg * 4 + r;
#pragma unroll
                for (int t = 0; t < 4; ++t) {
                    const int j = kt + 16 * t + col;
                    const bool valid = (j >= 0) && (j < S_LEN) &&
                                       (j >= qq - WIN) && (j <= qq + WIN);
                    if (!valid) st[t] = -1e30f;
                }
            }
            float tmax = fmaxf(fmaxf(st[0], st[1]), fmaxf(st[2], st[3]));
            tmax = fmaxf(tmax, __shfl_xor(tmax, 1));
            tmax = fmaxf(tmax, __shfl_xor(tmax, 2));
            tmax = fmaxf(tmax, __shfl_xor(tmax, 4));
            tmax = fmaxf(tmax, __shfl_xor(tmax, 8));
            const float mnew = fmaxf(mrow[r], tmax);
            alpha[r] = __expf(mrow[r] - mnew);
            mrow[r] = mnew;
            float rs = 0.f;
#pragma unroll
            for (int t = 0; t < 4; ++t) {
                // gate on raw score: avoids exp(0)=1 when a whole row is masked
                const float pv = (st[t] > -1e29f) ? __expf(st[t] - mnew) : 0.f;
                p[r][t] = pv;
                rs += pv;
            }
            rs += __shfl_xor(rs, 1);
            rs += __shfl_xor(rs, 2);
            rs += __shfl_xor(rs, 4);
            rs += __shfl_xor(rs, 8);
            lrow[r] = lrow[r] * alpha[r] + rs;
        }

        // rescale O accumulators (rows match C-layout rows)
#pragma unroll
        for (int dt = 0; dt < 4; ++dt) {
#pragma unroll
            for (int r = 0; r < 4; ++r) Oacc[dt][r] *= alpha[r];
        }

        // ---- P: C-layout -> LDS -> A-layout ----
#pragma unroll
        for (int r = 0; r < 4; ++r)
#pragma unroll
            for (int t = 0; t < 4; ++t)
                Psh[w][kg * 4 + r][t * 16 + col] = f2bf(p[r][t]);
        // same-wave RAW on LDS: in-order per wave; compiler inserts lgkmcnt

        const short* pp = &Psh[w][col][kg * 8];
        const short8 pA0 = *(const short8*)(pp);
        const short8 pA1 = *(const short8*)(pp + 32);

        // ---- PV ----
#pragma unroll
        for (int dt = 0; dt < 4; ++dt) {
            const short* vp2 = &Vsh[dt * 16 + col][kg * 8];
            const short8 vB0 = *(const short8*)(vp2);
            const short8 vB1 = *(const short8*)(vp2 + 32);
            Oacc[dt] = __builtin_amdgcn_mfma_f32_16x16x32_bf16(pA0, vB0, Oacc[dt], 0, 0, 0);
            Oacc[dt] = __builtin_amdgcn_mfma_f32_16x16x32_bf16(pA1, vB1, Oacc[dt], 0, 0, 0);
        }
    }

    // ---- epilogue: out[b][s][h*64 + d] fp32 ----
    const int b = bh >> 3, h = bh & 7;
#pragma unroll
    for (int r = 0; r < 4; ++r) {
        const float inv = 1.0f / lrow[r];
        const int qpos = q0 + kg * 4 + r;
        float* op = out + ((size_t)(b * S_LEN + qpos)) * D_MODEL + h * HD + col;
#pragma unroll
        for (int dt = 0; dt < 4; ++dt) op[dt * 16] = Oacc[dt][r] * inv;
    }
}

// ---------------------------------------------------------------------------
extern "C" void kernel_launch(void* const* d_in, const int* in_sizes, int n_in,
                              void* d_out, int out_size, void* d_ws, size_t ws_size,
                              hipStream_t stream)
{
    const float* x  = (const float*)d_in[0];
    const float* Wq = (const float*)d_in[1];
    const float* bq = (const float*)d_in[2];
    const float* Wk = (const float*)d_in[3];
    const float* bk = (const float*)d_in[4];
    const float* Wv = (const float*)d_in[5];
    const float* bv = (const float*)d_in[6];
    float* out = (float*)d_out;

    const size_t n_elem = (size_t)NB * NH * S_LEN * HD;   // 8,388,608
    bf16* qw = (bf16*)d_ws;
    bf16* kw = qw + n_elem;
    bf16* vw = kw + n_elem;

    dim3 pgrid(D_MODEL / 64, (NB * S_LEN) / 64);           // (8, 256)
    proj_kernel<<<pgrid, 256, 0, stream>>>(x, Wq, bq, qw, 0.125f);
    proj_kernel<<<pgrid, 256, 0, stream>>>(x, Wk, bk, kw, 1.0f);
    proj_kernel<<<pgrid, 256, 0, stream>>>(x, Wv, bv, vw, 1.0f);

    dim3 agrid(NB * NH, S_LEN / 64);                       // (16, 128)
    attn_mfma_kernel<<<agrid, 256, 0, stream>>>(qw, kw, vw, out);
}

// Round 3
// 224.287 us; speedup vs baseline: 4.1926x; 2.4009x over previous
//
#include <hip/hip_runtime.h>
#include <hip/hip_bf16.h>

#define S_LEN 8192
#define D_MODEL 512
#define NH 8
#define HD 64
#define WIN 256
#define NB 2

typedef __hip_bfloat16 bf16;
typedef __attribute__((ext_vector_type(8))) short short8;
typedef __attribute__((ext_vector_type(4))) float f32x4;

static __device__ __forceinline__ short f2bf(float f) {
    bf16 h = __float2bfloat16(f);
    return *reinterpret_cast<short*>(&h);
}

static __device__ __forceinline__ void gload_lds16(short* lds, const short* g) {
    __builtin_amdgcn_global_load_lds(
        (const __attribute__((address_space(1))) void*)g,
        (__attribute__((address_space(3))) void*)lds, 16, 0, 0);
}

// ---------------------------------------------------------------------------
// x (fp32 [16384][512]) -> xb (bf16), flat convert
// ---------------------------------------------------------------------------
__global__ __launch_bounds__(256) void convert_x_kernel(
    const float* __restrict__ x, short* __restrict__ xb)
{
    const int n4 = (NB * S_LEN * D_MODEL) / 4;   // 2,097,152
    for (int i = blockIdx.x * 256 + threadIdx.x; i < n4; i += gridDim.x * 256) {
        float4 v = ((const float4*)x)[i];
        short4 o;
        o.x = f2bf(v.x); o.y = f2bf(v.y); o.z = f2bf(v.z); o.w = f2bf(v.w);
        ((short4*)xb)[i] = o;
    }
}

// ---------------------------------------------------------------------------
// W (fp32 [k][n]) -> wT (bf16 [n][k]) for the 3 weights (blockIdx.z)
// ---------------------------------------------------------------------------
__global__ __launch_bounds__(256) void convert_wT_kernel(
    const float* __restrict__ Wq, const float* __restrict__ Wk,
    const float* __restrict__ Wv, short* __restrict__ wT)
{
    __shared__ float t[32][33];
    const float* W = blockIdx.z == 0 ? Wq : (blockIdx.z == 1 ? Wk : Wv);
    const int n0 = blockIdx.x * 32, k0 = blockIdx.y * 32;
    const int tx = threadIdx.x & 31, ty = threadIdx.x >> 5;   // ty 0..7
#pragma unroll
    for (int i = 0; i < 4; ++i)
        t[ty + 8 * i][tx] = W[(size_t)(k0 + ty + 8 * i) * D_MODEL + n0 + tx];
    __syncthreads();
#pragma unroll
    for (int i = 0; i < 4; ++i) {
        const int nl = ty + 8 * i, kl = tx;
        wT[(size_t)blockIdx.z * D_MODEL * D_MODEL +
           (size_t)(n0 + nl) * D_MODEL + k0 + kl] = f2bf(t[kl][nl]);
    }
}

// ---------------------------------------------------------------------------
// bf16 MFMA projection GEMM: C = xb @ wT^T (+bias)*scale -> head-major bf16.
// 128x128 tile, BK=64, 4 waves (each 64x64 sub-tile, 4x4 of 16x16x32 MFMAs).
// Staging via global_load_lds(16B) with rotate-swizzle: chunk(m,kc) stored at
// m*8 + ((kc + (m>>1)) & 7)  -> both staging (no padding allowed) and
// ds_read_b128 frag reads hit every bank-group exactly 2x (free, m136).
// grid = (12, 128): x-dim = weight*4 + ntile, y = mtile.
// ---------------------------------------------------------------------------
__global__ __launch_bounds__(256) void proj_mfma_kernel(
    const short* __restrict__ xb, const short* __restrict__ wT,
    const float* __restrict__ bq, const float* __restrict__ bk,
    const float* __restrict__ bv, bf16* __restrict__ qkv)
{
    __shared__ short Ash[128 * 64];   // 16 KB, swizzled
    __shared__ short Bsh[128 * 64];   // 16 KB, swizzled

    const int widx = blockIdx.x >> 2;
    const int col0 = (blockIdx.x & 3) * 128;
    const int row0 = blockIdx.y * 128;
    const int tid  = threadIdx.x;
    const int w    = tid >> 6;
    const int lane = tid & 63;
    const int col  = lane & 15;
    const int kg   = lane >> 4;

    const float* bias = widx == 0 ? bq : (widx == 1 ? bk : bv);
    const float scale = widx == 0 ? 0.125f : 1.0f;
    const short* wbase = wT + (size_t)widx * D_MODEL * D_MODEL;

    const f32x4 zero4 = {0.f, 0.f, 0.f, 0.f};
    f32x4 acc[4][4];
#pragma unroll
    for (int i = 0; i < 4; ++i)
#pragma unroll
        for (int j = 0; j < 4; ++j) acc[i][j] = zero4;

    const int wm0 = (w >> 1) * 64;
    const int wn0 = (w & 1) * 64;

    for (int kb = 0; kb < D_MODEL; kb += 64) {
        // ---- stage A (x rows) and B (wT rows), 1024 chunks each ----
#pragma unroll
        for (int ci = 0; ci < 4; ++ci) {
            const int Lb = w * 256 + ci * 64;
            const int L  = Lb + lane;
            const int m  = L >> 3;
            const int kc = ((L & 7) - (m >> 1)) & 7;
            const int ko = kb + kc * 8;
            gload_lds16(Ash + (size_t)Lb * 8,
                        xb + (size_t)(row0 + m) * D_MODEL + ko);
            gload_lds16(Bsh + (size_t)Lb * 8,
                        wbase + (size_t)(col0 + m) * D_MODEL + ko);
        }
        __syncthreads();

#pragma unroll
        for (int s = 0; s < 2; ++s) {
            short8 af[4], bfr[4];
#pragma unroll
            for (int mt = 0; mt < 4; ++mt) {
                const int m = wm0 + mt * 16 + col;
                const int c = m * 8 + ((s * 4 + kg + (m >> 1)) & 7);
                af[mt] = *(const short8*)(Ash + (size_t)c * 8);
            }
#pragma unroll
            for (int nt = 0; nt < 4; ++nt) {
                const int n = wn0 + nt * 16 + col;
                const int c = n * 8 + ((s * 4 + kg + (n >> 1)) & 7);
                bfr[nt] = *(const short8*)(Bsh + (size_t)c * 8);
            }
#pragma unroll
            for (int mt = 0; mt < 4; ++mt)
#pragma unroll
                for (int nt = 0; nt < 4; ++nt)
                    acc[mt][nt] = __builtin_amdgcn_mfma_f32_16x16x32_bf16(
                        af[mt], bfr[nt], acc[mt][nt], 0, 0, 0);
        }
        __syncthreads();
    }

    // ---- epilogue: (acc + bias) * scale -> bf16 head-major [b*8+h][s][d] ----
    bf16* dst = qkv + (size_t)widx * (NB * NH * S_LEN * HD);
#pragma unroll
    for (int nt = 0; nt < 4; ++nt) {
        const int n = col0 + wn0 + nt * 16 + col;     // 0..511
        const float bias_v = bias[n];
        const int h = n >> 6, d = n & 63;
#pragma unroll
        for (int mt = 0; mt < 4; ++mt) {
#pragma unroll
            for (int r = 0; r < 4; ++r) {
                const int m = row0 + wm0 + mt * 16 + kg * 4 + r;
                const int b = m >> 13, s2 = m & (S_LEN - 1);
                dst[(((size_t)(b * NH + h)) * S_LEN + s2) * HD + d] =
                    __float2bfloat16((acc[mt][nt][r] + bias_v) * scale);
            }
        }
    }
}

// ---------------------------------------------------------------------------
// Fallback fp32 projection (used only if ws_size is too small for bf16 path)
// ---------------------------------------------------------------------------
__global__ __launch_bounds__(256) void proj_kernel(
    const float* __restrict__ x, const float* __restrict__ Wm,
    const float* __restrict__ bias, bf16* __restrict__ dst, float scale)
{
    __shared__ float As[16][64];
    __shared__ float Bs[16][64];
    const int tid  = threadIdx.x;
    const int row0 = blockIdx.y * 64;
    const int col0 = blockIdx.x * 64;
    const int ty = tid >> 4, tx = tid & 15;
    const int t4 = tid * 4;
    const int ai = t4 >> 4, aj = t4 & 15;
    const int bj = t4 >> 6, bi = t4 & 63;
    float acc[4][4] = {};
    for (int kb = 0; kb < D_MODEL; kb += 16) {
        float4 av = *(const float4*)(x  + (size_t)(row0 + ai) * D_MODEL + kb + aj);
        float4 bv = *(const float4*)(Wm + (size_t)(kb + bj)  * D_MODEL + col0 + bi);
        As[aj + 0][ai] = av.x; As[aj + 1][ai] = av.y;
        As[aj + 2][ai] = av.z; As[aj + 3][ai] = av.w;
        *(float4*)(&Bs[bj][bi]) = bv;
        __syncthreads();
#pragma unroll
        for (int k = 0; k < 16; ++k) {
            float a[4], b[4];
#pragma unroll
            for (int ii = 0; ii < 4; ++ii) a[ii] = As[k][ty * 4 + ii];
#pragma unroll
            for (int jj = 0; jj < 4; ++jj) b[jj] = Bs[k][tx * 4 + jj];
#pragma unroll
            for (int ii = 0; ii < 4; ++ii)
#pragma unroll
                for (int jj = 0; jj < 4; ++jj) acc[ii][jj] += a[ii] * b[jj];
        }
        __syncthreads();
    }
#pragma unroll
    for (int ii = 0; ii < 4; ++ii) {
        const int m = row0 + ty * 4 + ii;
        const int b = m >> 13, s = m & (S_LEN - 1);
#pragma unroll
        for (int jj = 0; jj < 4; ++jj) {
            const int n = col0 + tx * 4 + jj;
            const int h = n >> 6, d = n & 63;
            dst[(((size_t)(b * NH + h)) * S_LEN + s) * HD + d] =
                __float2bfloat16((acc[ii][jj] + bias[n]) * scale);
        }
    }
}

// ---------------------------------------------------------------------------
// Flash-style MFMA sliding-window attention (unchanged from round 2).
// ---------------------------------------------------------------------------
__global__ __launch_bounds__(256) void attn_mfma_kernel(
    const bf16* __restrict__ qw, const bf16* __restrict__ kw,
    const bf16* __restrict__ vw, float* __restrict__ out)
{
    __shared__ __align__(16) short Vsh[64][72];
    __shared__ __align__(16) short Psh[4][16][72];

    const int bh   = blockIdx.x;
    const int qt0  = blockIdx.y * 64;
    const int tid  = threadIdx.x;
    const int w    = tid >> 6;
    const int lane = tid & 63;
    const int col  = lane & 15;
    const int kg   = lane >> 4;
    const int q0   = qt0 + w * 16;
    const size_t base = (size_t)bh * S_LEN * HD;

    const short* qg  = (const short*)qw;
    const short* kgp = (const short*)kw;
    const short* vgp = (const short*)vw;

    const short* qptr = qg + base + (size_t)(q0 + col) * HD + kg * 8;
    const short8 qA0 = *(const short8*)(qptr);
    const short8 qA1 = *(const short8*)(qptr + 32);

    const f32x4 zero4 = {0.f, 0.f, 0.f, 0.f};
    f32x4 Oacc[4] = {zero4, zero4, zero4, zero4};
    float mrow[4] = {-1e30f, -1e30f, -1e30f, -1e30f};
    float lrow[4] = {0.f, 0.f, 0.f, 0.f};

    const int vkey = tid & 63;
    const int vd0  = (tid >> 6) * 16;

    for (int kt = qt0 - WIN; kt <= qt0 + WIN; kt += 64) {
        if (kt + 63 < 0 || kt >= S_LEN) continue;

        __syncthreads();
        {
            const int j  = kt + vkey;
            const int jc = j < 0 ? 0 : (j >= S_LEN ? S_LEN - 1 : j);
            const short* vp = vgp + base + (size_t)jc * HD + vd0;
            const short8 v0 = *(const short8*)(vp);
            const short8 v1 = *(const short8*)(vp + 8);
#pragma unroll
            for (int i = 0; i < 8; ++i) {
                Vsh[vd0 + i][vkey]     = v0[i];
                Vsh[vd0 + 8 + i][vkey] = v1[i];
            }
        }
        __syncthreads();

        const bool need_mask = (kt < 0) || (kt + 63 >= S_LEN) ||
                               (kt == qt0 - WIN) || (kt == qt0 + WIN);

        f32x4 sc[4];
#pragma unroll
        for (int t = 0; t < 4; ++t) {
            const int j  = kt + 16 * t + col;
            const int jc = j < 0 ? 0 : (j >= S_LEN ? S_LEN - 1 : j);
            const short* kp = kgp + base + (size_t)jc * HD + kg * 8;
            const short8 kB0 = *(const short8*)(kp);
            const short8 kB1 = *(const short8*)(kp + 32);
            f32x4 a = zero4;
            a = __builtin_amdgcn_mfma_f32_16x16x32_bf16(qA0, kB0, a, 0, 0, 0);
            a = __builtin_amdgcn_mfma_f32_16x16x32_bf16(qA1, kB1, a, 0, 0, 0);
            sc[t] = a;
        }

        float p[4][4];
        float alpha[4];
#pragma unroll
        for (int r = 0; r < 4; ++r) {
            float st[4];
#pragma unroll
            for (int t = 0; t < 4; ++t) st[t] = sc[t][r];
            if (need_mask) {
                const int qq = q0 + kg * 4 + r;
#pragma unroll
                for (int t = 0; t < 4; ++t) {
                    const int j = kt + 16 * t + col;
                    const bool valid = (j >= 0) && (j < S_LEN) &&
                                       (j >= qq - WIN) && (j <= qq + WIN);
                    if (!valid) st[t] = -1e30f;
                }
            }
            float tmax = fmaxf(fmaxf(st[0], st[1]), fmaxf(st[2], st[3]));
            tmax = fmaxf(tmax, __shfl_xor(tmax, 1));
            tmax = fmaxf(tmax, __shfl_xor(tmax, 2));
            tmax = fmaxf(tmax, __shfl_xor(tmax, 4));
            tmax = fmaxf(tmax, __shfl_xor(tmax, 8));
            const float mnew = fmaxf(mrow[r], tmax);
            alpha[r] = __expf(mrow[r] - mnew);
            mrow[r] = mnew;
            float rs = 0.f;
#pragma unroll
            for (int t = 0; t < 4; ++t) {
                const float pv = (st[t] > -1e29f) ? __expf(st[t] - mnew) : 0.f;
                p[r][t] = pv;
                rs += pv;
            }
            rs += __shfl_xor(rs, 1);
            rs += __shfl_xor(rs, 2);
            rs += __shfl_xor(rs, 4);
            rs += __shfl_xor(rs, 8);
            lrow[r] = lrow[r] * alpha[r] + rs;
        }

#pragma unroll
        for (int dt = 0; dt < 4; ++dt)
#pragma unroll
            for (int r = 0; r < 4; ++r) Oacc[dt][r] *= alpha[r];

#pragma unroll
        for (int r = 0; r < 4; ++r)
#pragma unroll
            for (int t = 0; t < 4; ++t)
                Psh[w][kg * 4 + r][t * 16 + col] = f2bf(p[r][t]);

        const short* pp = &Psh[w][col][kg * 8];
        const short8 pA0 = *(const short8*)(pp);
        const short8 pA1 = *(const short8*)(pp + 32);

#pragma unroll
        for (int dt = 0; dt < 4; ++dt) {
            const short* vp2 = &Vsh[dt * 16 + col][kg * 8];
            const short8 vB0 = *(const short8*)(vp2);
            const short8 vB1 = *(const short8*)(vp2 + 32);
            Oacc[dt] = __builtin_amdgcn_mfma_f32_16x16x32_bf16(pA0, vB0, Oacc[dt], 0, 0, 0);
            Oacc[dt] = __builtin_amdgcn_mfma_f32_16x16x32_bf16(pA1, vB1, Oacc[dt], 0, 0, 0);
        }
    }

    const int b = bh >> 3, h = bh & 7;
#pragma unroll
    for (int r = 0; r < 4; ++r) {
        const float inv = 1.0f / lrow[r];
        const int qpos = q0 + kg * 4 + r;
        float* op = out + ((size_t)(b * S_LEN + qpos)) * D_MODEL + h * HD + col;
#pragma unroll
        for (int dt = 0; dt < 4; ++dt) op[dt * 16] = Oacc[dt][r] * inv;
    }
}

// ---------------------------------------------------------------------------
extern "C" void kernel_launch(void* const* d_in, const int* in_sizes, int n_in,
                              void* d_out, int out_size, void* d_ws, size_t ws_size,
                              hipStream_t stream)
{
    const float* x  = (const float*)d_in[0];
    const float* Wq = (const float*)d_in[1];
    const float* bq = (const float*)d_in[2];
    const float* Wk = (const float*)d_in[3];
    const float* bk = (const float*)d_in[4];
    const float* Wv = (const float*)d_in[5];
    const float* bv = (const float*)d_in[6];
    float* out = (float*)d_out;

    const size_t n_elem = (size_t)NB * NH * S_LEN * HD;       // 8,388,608
    bf16* qw = (bf16*)d_ws;
    bf16* kw = qw + n_elem;
    bf16* vw = kw + n_elem;
    short* xb = (short*)(vw + n_elem);                        // 16384x512 bf16
    short* wT = xb + (size_t)NB * S_LEN * D_MODEL;            // 3x512x512 bf16

    const size_t need = (3 * n_elem + (size_t)NB * S_LEN * D_MODEL +
                         3 * (size_t)D_MODEL * D_MODEL) * sizeof(short);

    if (ws_size >= need) {
        convert_x_kernel<<<2048, 256, 0, stream>>>(x, xb);
        dim3 wgrid(D_MODEL / 32, D_MODEL / 32, 3);
        convert_wT_kernel<<<wgrid, 256, 0, stream>>>(Wq, Wk, Wv, wT);
        dim3 ggrid(12, (NB * S_LEN) / 128);                   // (12, 128)
        proj_mfma_kernel<<<ggrid, 256, 0, stream>>>(xb, wT, bq, bk, bv, qw);
    } else {
        dim3 pgrid(D_MODEL / 64, (NB * S_LEN) / 64);
        proj_kernel<<<pgrid, 256, 0, stream>>>(x, Wq, bq, qw, 0.125f);
        proj_kernel<<<pgrid, 256, 0, stream>>>(x, Wk, bk, kw, 1.0f);
        proj_kernel<<<pgrid, 256, 0, stream>>>(x, Wv, bv, vw, 1.0f);
    }

    dim3 agrid(NB * NH, S_LEN / 64);                          // (16, 128)
    attn_mfma_kernel<<<agrid, 256, 0, stream>>>(qw, kw, vw, out);
}